// Round 6
// baseline (262.192 us; speedup 1.0000x reference)
//
#include <hip/hip_runtime.h>

// RecurrentGCN (DCRNN cell, K=1) — MFMA version, round 6: FENCE-FREE loop.
// R5 post-mortem: paired-tile ILP (2x work between fences) gained nothing;
// R2 showed VALU cuts gain nothing. The invariant across all ~30%-busy
// kernels is the 3x per-tile LDS write -> s_waitcnt lgkmcnt(0) -> read
// round-trip. This round removes the structure:
//  * operand swap: GEMMs computed as W^T x F (A=weights, B=features).
//    C-frag then holds 8 channels of ONE node per lane; the next GEMM's
//    B-frag needs 8 k's of the SAME node -> a 4-lane-group shuffle done
//    in-register with 8 ds_bpermute + 4 selects (no write, no fence).
//  * B-frags of [x|h] are 16B row-chunks of node c16 -> loaded DIRECTLY
//    from global (L2/L3-warm). No staging LDS at all; LDS = 13.8KB weight
//    images (setup only). Loop has ZERO ds_write / lgkmcnt(0).
//  * v_rcp_f32 instead of IEEE division in sigmoid/tanh.

#define N_NODES 500000
#define IN_DIM  16
#define HID     32
#define OUT_DIM 8
#define XH      48         // IN_DIM + HID
#define NTILES  31250      // N_NODES / 16 (exact)
#define WROW    72         // sW row stride in bf16 (64 k-pad + 8)

typedef unsigned int u32;
typedef unsigned short u16;
typedef __attribute__((ext_vector_type(8))) short bf16x8;  // 8 bf16 = 4 VGPR
typedef __attribute__((ext_vector_type(4))) float f32x4;   // MFMA 16x16 acc

static __device__ __forceinline__ float bfbits(u32 hi){ union{u32 x; float f;} t; t.x=hi; return t.f; }
static __device__ __forceinline__ float bflo(u32 u){ return bfbits(u<<16); }
static __device__ __forceinline__ float bfhi(u32 u){ return bfbits(u & 0xffff0000u); }
static __device__ __forceinline__ float bf2f(u16 s){ return bfbits(((u32)s)<<16); }
static __device__ __forceinline__ u32 cvtpk(float a, float b){
    u32 r; asm("v_cvt_pk_bf16_f32 %0, %1, %2" : "=v"(r) : "v"(a), "v"(b)); return r;
}
static __device__ __forceinline__ u16 f2bf(float f){
    union{float f;u32 x;} t; t.f=f; u32 x=t.x;
    return (u16)((x + 0x7fffu + ((x>>16)&1u)) >> 16);      // RNE
}
static __device__ __forceinline__ float rcp_(float x){
    float r; asm("v_rcp_f32 %0, %1" : "=v"(r) : "v"(x)); return r;
}
static __device__ __forceinline__ float sigm(float a){
    return rcp_(1.f + __expf(-a));       // saturates: exp->inf => rcp->0; exp->0 => 1
}
static __device__ __forceinline__ float tanh_(float a){
    float e = __expf(-2.f * fabsf(a));
    return __builtin_copysignf((1.f - e) * rcp_(1.f + e), a);
}
#define MFMA16(a,b,c) __builtin_amdgcn_mfma_f32_16x16x32_bf16(a,b,c,0,0,0)
#define BPERM(i,v)    ((u32)__builtin_amdgcn_ds_bpermute((int)(i),(int)(v)))

static __device__ __forceinline__ float ldf(const void* p, int i, bool F32){
    return F32 ? ((const float*)p)[i] : bf2f(((const u16*)p)[i]);
}
// combined DConv weight: w[0][k][c] + w[1][k][c], layout [2][48][32]
static __device__ __forceinline__ float wsum(const void* wp, int k, int c, bool F32){
    int i0 = k*HID + c;
    return ldf(wp, i0, F32) + ldf(wp, XH*HID + i0, F32);
}

__global__ __launch_bounds__(256)
void rgcn_kernel(const void* __restrict__ xp_,   // [N,16]
                 const void* __restrict__ hp_,   // [N,32]
                 const void* __restrict__ wz_, const void* __restrict__ bz_,
                 const void* __restrict__ wr_, const void* __restrict__ br_,
                 const void* __restrict__ wh_, const void* __restrict__ bh_,
                 const void* __restrict__ wl_, const void* __restrict__ bl_,
                 void* __restrict__ dout_)       // out [N,8] ++ h_new [N,32]
{
    __shared__ u16 sW[3][32*WROW];     // combined bf16 weights, [col j][k+pad]
    __shared__ int sF32;

    const int tid = threadIdx.x;

    // ---- dtype detection
    if (tid < 64) {
        const u32* xw = (const u32*)xp_;
        int bad = 0;
#pragma unroll
        for (int q = 0; q < 2; q++) {
            float lo = bflo(xw[tid*2 + q]);
            if (!(fabsf(lo) <= 1e6f)) bad = 1;
        }
        unsigned long long m = __ballot(bad);
        if (tid == 0) sF32 = (m != 0ull) ? 1 : 0;
    }
    __syncthreads();
    const bool F32 = (sF32 != 0);

    // ---- block-cooperative weight prep: sW[m][j][k] = bf16(w[0][k][j]+w[1][k][j])
    {
        const void* wsrc[3] = { wz_, wr_, wh_ };
#pragma unroll
        for (int m = 0; m < 3; m++) {
            u32* dst = (u32*)sW[m];
            for (int o = tid; o < 32*(WROW/2); o += 256) {
                int c = o / (WROW/2), kk = o - c*(WROW/2);
                int k0 = 2*kk, k1 = 2*kk + 1;
                float v0 = (k0 < XH) ? wsum(wsrc[m], k0, c, F32) : 0.f;
                float v1 = (k1 < XH) ? wsum(wsrc[m], k1, c, F32) : 0.f;
                dst[o] = cvtpk(v0, v1);
            }
        }
    }
    __syncthreads();

    const int lane = tid & 63, wv = tid >> 6;
    const int c16 = lane & 15, g = lane >> 4;
    const bool gLow = (g < 2);

    // bpermute byte-indices for the lane-group transpose (loop-invariant)
    const int idxA = (c16 + 32*(g & 1)) * 4;
    const int idxB = idxA + 64;

    // ---- per-lane bias seeds: channel j = jt*16 + g*4 + rr
    float bzv[2][4], brv[2][4], bhv[2][4], blv[4];
#pragma unroll
    for (int jt = 0; jt < 2; jt++)
#pragma unroll
        for (int rr = 0; rr < 4; rr++) {
            int j = jt*16 + g*4 + rr;
            bzv[jt][rr] = ldf(bz_, j, F32);
            brv[jt][rr] = ldf(br_, j, F32);
            bhv[jt][rr] = ldf(bh_, j, F32);
        }
#pragma unroll
    for (int rr = 0; rr < 4; rr++) {
        int o = g*4 + rr;
        blv[rr] = (o < OUT_DIM) ? ldf(bl_, o, F32) : 0.f;
    }

    // ---- weight A-fragments (A row = lane&15 -> channel j = jt*16+c16; k = g*8+e)
    bf16x8 Az[2][2], Ar[2][2], Ah[2][2], Al;
#pragma unroll
    for (int jt = 0; jt < 2; jt++)
#pragma unroll
        for (int kt = 0; kt < 2; kt++) {
            int off = (jt*16 + c16)*(WROW*2) + (kt*32 + g*8)*2;
            Az[jt][kt] = *(const bf16x8*)((const char*)sW[0] + off);
            Ar[jt][kt] = *(const bf16x8*)((const char*)sW[1] + off);
            Ah[jt][kt] = *(const bf16x8*)((const char*)sW[2] + off);
        }
    {
        union { u16 us[8]; bf16x8 v; } ul;
#pragma unroll
        for (int e = 0; e < 8; e++) {
            int k = g*8 + e;   // hid index
            float v = (c16 < OUT_DIM) ? ldf(wl_, k*OUT_DIM + c16, F32) : 0.f;
            ul.us[e] = f2bf(v);
        }
        Al = ul.v;
    }

    float* outF = (float*)dout_;
    float* hnF  = outF + (size_t)N_NODES * OUT_DIM;
    u16*   outB = (u16*)dout_;
    u16*   hnB  = outB + (size_t)N_NODES * OUT_DIM;

    const int wid = blockIdx.x*4 + wv;
    const int nw  = gridDim.x*4;

    // ---- depth-1 prefetch regs: B-frag chunks + glue-h, all per-node-row
    uint4 pk0a, pk0b, pk1a, pk1b, phv0, phv1;
#define PLOAD(TT) do { \
        size_t nr = (size_t)(TT)*16 + c16; \
        if (F32) { \
            const char* xr = (const char*)xp_ + nr*64; \
            const char* hr = (const char*)hp_ + nr*128; \
            const char* p0 = gLow ? (xr + g*32) : (hr + (g-2)*32); \
            pk0a = *(const uint4*)p0; pk0b = *(const uint4*)(p0 + 16); \
            if (gLow) { \
                pk1a = *(const uint4*)(hr + 64 + g*32); \
                pk1b = *(const uint4*)(hr + 80 + g*32); \
            } \
            phv0 = *(const uint4*)(hr + g*16); \
            phv1 = *(const uint4*)(hr + 64 + g*16); \
        } else { \
            const char* xr = (const char*)xp_ + nr*32; \
            const char* hr = (const char*)hp_ + nr*64; \
            const char* p0 = gLow ? (xr + g*16) : (hr + (g-2)*16); \
            pk0a = *(const uint4*)p0; \
            if (gLow) pk1a = *(const uint4*)(hr + 32 + g*16); \
            uint2 a = *(const uint2*)(hr + g*8); \
            uint2 b = *(const uint2*)(hr + 32 + g*8); \
            phv0.x = a.x; phv0.y = a.y; phv1.x = b.x; phv1.y = b.y; \
        } \
    } while (0)

    if (wid < NTILES) PLOAD(wid);

    for (int t = wid; t < NTILES; t += nw) {
        const size_t nb = (size_t)t * 16;

        // ---- extract prefetched data into frags/regs (frees prefetch regs)
        u32 f0w[4], f1w[4];
        float hvf[8];
        if (F32) {
            f0w[0] = cvtpk(bfbits(0)+0.f, 0.f), f0w[0] = cvtpk(((const float*)&pk0a)[0], ((const float*)&pk0a)[1]);
            f0w[1] = cvtpk(((const float*)&pk0a)[2], ((const float*)&pk0a)[3]);
            f0w[2] = cvtpk(((const float*)&pk0b)[0], ((const float*)&pk0b)[1]);
            f0w[3] = cvtpk(((const float*)&pk0b)[2], ((const float*)&pk0b)[3]);
            f1w[0] = cvtpk(((const float*)&pk1a)[0], ((const float*)&pk1a)[1]);
            f1w[1] = cvtpk(((const float*)&pk1a)[2], ((const float*)&pk1a)[3]);
            f1w[2] = cvtpk(((const float*)&pk1b)[0], ((const float*)&pk1b)[1]);
            f1w[3] = cvtpk(((const float*)&pk1b)[2], ((const float*)&pk1b)[3]);
#pragma unroll
            for (int q = 0; q < 4; q++) {
                hvf[q]   = ((const float*)&phv0)[q];
                hvf[4+q] = ((const float*)&phv1)[q];
            }
        } else {
            f0w[0] = pk0a.x; f0w[1] = pk0a.y; f0w[2] = pk0a.z; f0w[3] = pk0a.w;
            f1w[0] = pk1a.x; f1w[1] = pk1a.y; f1w[2] = pk1a.z; f1w[3] = pk1a.w;
            hvf[0] = bflo(phv0.x); hvf[1] = bfhi(phv0.x);
            hvf[2] = bflo(phv0.y); hvf[3] = bfhi(phv0.y);
            hvf[4] = bflo(phv1.x); hvf[5] = bfhi(phv1.x);
            hvf[6] = bflo(phv1.y); hvf[7] = bfhi(phv1.y);
        }
        union { u32 w[4]; bf16x8 v; } uf0, uf1;
#pragma unroll
        for (int q = 0; q < 4; q++) {
            uf0.w[q] = f0w[q];
            uf1.w[q] = gLow ? f1w[q] : 0u;      // kt1 pad rows (k>=48) are zero
        }
        bf16x8 Fk0 = uf0.v, Fk1 = uf1.v;

        // ---- issue NEXT tile's loads (counted vmcnt; consumed next iter)
        { int tn = t + nw; if (tn < NTILES) PLOAD(tn); }

        // ---- GEMM1: z and r preacts, D[j][node], bias-seeded
        f32x4 accZ[2], accR[2];
#pragma unroll
        for (int jt = 0; jt < 2; jt++) {
            f32x4 az; az[0]=bzv[jt][0]; az[1]=bzv[jt][1]; az[2]=bzv[jt][2]; az[3]=bzv[jt][3];
            az = MFMA16(Az[jt][0], Fk0, az);
            az = MFMA16(Az[jt][1], Fk1, az);
            accZ[jt] = az;
            f32x4 ar; ar[0]=brv[jt][0]; ar[1]=brv[jt][1]; ar[2]=brv[jt][2]; ar[3]=brv[jt][3];
            ar = MFMA16(Ar[jt][0], Fk0, ar);
            ar = MFMA16(Ar[jt][1], Fk1, ar);
            accR[jt] = ar;
        }

        // ---- glue 1 (pure registers): z, r -> hr = h*r, packed P/Q words
        float zv[2][4];
        float hr0[4], hr1[4];
#pragma unroll
        for (int rr = 0; rr < 4; rr++) {
            zv[0][rr] = sigm(accZ[0][rr]);
            zv[1][rr] = sigm(accZ[1][rr]);
            hr0[rr] = hvf[rr]     * sigm(accR[0][rr]);
            hr1[rr] = hvf[4+rr]   * sigm(accR[1][rr]);
        }
        u32 P0 = cvtpk(hr0[0], hr0[1]), P1 = cvtpk(hr0[2], hr0[3]);
        u32 Q0 = cvtpk(hr1[0], hr1[1]), Q1 = cvtpk(hr1[2], hr1[3]);

        // ---- in-register transpose: lane-group shuffle via ds_bpermute
        // dest g' needs hr[J..J+7], J = g'<2 ? 16+8g' : 8(g'-2)
        u32 qa0 = BPERM(idxA, Q0), pa0 = BPERM(idxA, P0);
        u32 qa1 = BPERM(idxA, Q1), pa1 = BPERM(idxA, P1);
        u32 qb0 = BPERM(idxB, Q0), pb0 = BPERM(idxB, P0);
        u32 qb1 = BPERM(idxB, Q1), pb1 = BPERM(idxB, P1);
        u32 W0 = gLow ? qa0 : pa0, W1 = gLow ? qa1 : pa1;
        u32 W2 = gLow ? qb0 : pb0, W3 = gLow ? qb1 : pb1;

        // assemble B2 = [x | hr]: kt0 = gLow ? x-chunk : hr[0..15]-chunk
        //                         kt1 = gLow ? hr[16..31]-chunk : zero
        union { u32 w[4]; bf16x8 v; } ub0, ub1;
        ub0.w[0] = gLow ? f0w[0] : W0; ub0.w[1] = gLow ? f0w[1] : W1;
        ub0.w[2] = gLow ? f0w[2] : W2; ub0.w[3] = gLow ? f0w[3] : W3;
        ub1.w[0] = gLow ? W0 : 0u;     ub1.w[1] = gLow ? W1 : 0u;
        ub1.w[2] = gLow ? W2 : 0u;     ub1.w[3] = gLow ? W3 : 0u;
        bf16x8 B2k0 = ub0.v, B2k1 = ub1.v;

        // ---- GEMMh: candidate preact
        f32x4 accH[2];
#pragma unroll
        for (int jt = 0; jt < 2; jt++) {
            f32x4 ah; ah[0]=bhv[jt][0]; ah[1]=bhv[jt][1]; ah[2]=bhv[jt][2]; ah[3]=bhv[jt][3];
            ah = MFMA16(Ah[jt][0], B2k0, ah);
            ah = MFMA16(Ah[jt][1], B2k1, ah);
            accH[jt] = ah;
        }

        // ---- glue 2: hn = ht + z*(h-ht); store hn direct; pack relu(hn)
        float rl0[4], rl1[4];
#pragma unroll
        for (int jt = 0; jt < 2; jt++) {
            float n0 = tanh_(accH[jt][0]); n0 = n0 + zv[jt][0]*(hvf[jt*4+0] - n0);
            float n1 = tanh_(accH[jt][1]); n1 = n1 + zv[jt][1]*(hvf[jt*4+1] - n1);
            float n2 = tanh_(accH[jt][2]); n2 = n2 + zv[jt][2]*(hvf[jt*4+2] - n2);
            float n3 = tanh_(accH[jt][3]); n3 = n3 + zv[jt][3]*(hvf[jt*4+3] - n3);
            if (F32) {
                float4 st; st.x=n0; st.y=n1; st.z=n2; st.w=n3;
                *(float4*)(hnF + (nb + c16)*HID + jt*16 + g*4) = st;
            } else {
                uint2 st; st.x = cvtpk(n0, n1); st.y = cvtpk(n2, n3);
                *(uint2*)(hnB + (nb + c16)*HID + jt*16 + g*4) = st;
            }
            float* rl = jt ? rl1 : rl0;
            rl[0] = fmaxf(n0, 0.f); rl[1] = fmaxf(n1, 0.f);
            rl[2] = fmaxf(n2, 0.f); rl[3] = fmaxf(n3, 0.f);
        }
        u32 RP0 = cvtpk(rl0[0], rl0[1]), RP1 = cvtpk(rl0[2], rl0[3]);
        u32 RQ0 = cvtpk(rl1[0], rl1[1]), RQ1 = cvtpk(rl1[2], rl1[3]);

        // ---- transpose relu(hn) -> B3 (k = g*8+e over 32): sel P for g<2
        u32 rpa0 = BPERM(idxA, RP0), rqa0 = BPERM(idxA, RQ0);
        u32 rpa1 = BPERM(idxA, RP1), rqa1 = BPERM(idxA, RQ1);
        u32 rpb0 = BPERM(idxB, RP0), rqb0 = BPERM(idxB, RQ0);
        u32 rpb1 = BPERM(idxB, RP1), rqb1 = BPERM(idxB, RQ1);
        union { u32 w[4]; bf16x8 v; } ub3;
        ub3.w[0] = gLow ? rpa0 : rqa0; ub3.w[1] = gLow ? rpa1 : rqa1;
        ub3.w[2] = gLow ? rpb0 : rqb0; ub3.w[3] = gLow ? rpb1 : rqb1;
        bf16x8 B3 = ub3.v;

        // ---- GEMMout: D2[o][node]; rows o>=8 are zero (Al rows zero, seed 0)
        f32x4 accO; accO[0]=blv[0]; accO[1]=blv[1]; accO[2]=blv[2]; accO[3]=blv[3];
        accO = MFMA16(Al, B3, accO);
        if (gLow) {
            if (F32) {
                float4 st; st.x=accO[0]; st.y=accO[1]; st.z=accO[2]; st.w=accO[3];
                *(float4*)(outF + (nb + c16)*OUT_DIM + g*4) = st;
            } else {
                uint2 st; st.x = cvtpk(accO[0], accO[1]); st.y = cvtpk(accO[2], accO[3]);
                *(uint2*)(outB + (nb + c16)*OUT_DIM + g*4) = st;
            }
        }
    }
#undef PLOAD
}

extern "C" void kernel_launch(void* const* d_in, const int* in_sizes, int n_in,
                              void* d_out, int out_size, void* d_ws, size_t ws_size,
                              hipStream_t stream) {
    // setup_inputs() order:
    // 0 x, 1 edge_index(unused), 2 edge_weight(unused), 3 h,
    // 4 w_z, 5 b_z, 6 w_r, 7 b_r, 8 w_h, 9 b_h, 10 w_lin, 11 b_lin
    const int block = 256;
    const int grid  = 2048;    // 8192 waves, grid-stride over 31250 tiles
    rgcn_kernel<<<grid, block, 0, stream>>>(
        d_in[0], d_in[3], d_in[4], d_in[5], d_in[6], d_in[7],
        d_in[8], d_in[9], d_in[10], d_in[11], d_out);
}

// Round 7
// 227.550 us; speedup vs baseline: 1.1522x; 1.1522x over previous
//
#include <hip/hip_runtime.h>

// RecurrentGCN (DCRNN cell, K=1) — MFMA version, round 7.
// R6 post-mortem: fence-free loop (VALU 21%) still ~100us -> the busy pipe is
// one the counters don't show: per-CU vector-memory address pipe (TA/TD).
// A wave-instr touching 64 distinct lines costs ~64cy there regardless of
// bytes. The shared uncoalesced region in ALL rounds is the weight prologue
// (wsum reads stride 128-256B/lane: ~54 instr x 64 lines per block ~= tens of
// us of per-CU serialization, duplicated by all 2048 blocks).
// THIS ROUND (single variable vs R4-92us): coalesced weight prologue —
// linear float4/uint4 reads of w0,w1 (9-27 coalesced instrs/block), sum in
// regs, transpose handled on the LDS-WRITE side (scattered ds_write is cheap).
// Loop body identical to R4.

#define N_NODES 500000
#define IN_DIM  16
#define HID     32
#define OUT_DIM 8
#define XH      48         // IN_DIM + HID
#define NTILES  31250      // N_NODES / 16 (exact)
#define WROW    72         // sW row stride in bf16 (64 k-pad + 8)

typedef unsigned int u32;
typedef unsigned short u16;
typedef __attribute__((ext_vector_type(8))) short bf16x8;  // 8 bf16 = 4 VGPR
typedef __attribute__((ext_vector_type(4))) float f32x4;   // MFMA 16x16 acc

static __device__ __forceinline__ float bfbits(u32 hi){ union{u32 x; float f;} t; t.x=hi; return t.f; }
static __device__ __forceinline__ float bflo(u32 u){ return bfbits(u<<16); }
static __device__ __forceinline__ float bfhi(u32 u){ return bfbits(u & 0xffff0000u); }
static __device__ __forceinline__ float bf2f(u16 s){ return bfbits(((u32)s)<<16); }
static __device__ __forceinline__ float u2f(u32 u){ union{u32 x; float f;} t; t.x=u; return t.f; }
static __device__ __forceinline__ u32 f2u(float f){ union{float f;u32 x;} t; t.f=f; return t.x; }
// packed f32->bf16 RNE, 1 instr (lo = a, hi = b)
static __device__ __forceinline__ u32 cvtpk(float a, float b){
    u32 r; asm("v_cvt_pk_bf16_f32 %0, %1, %2" : "=v"(r) : "v"(a), "v"(b)); return r;
}
static __device__ __forceinline__ u16 f2bf(float f){
    union{float f;u32 x;} t; t.f=f; u32 x=t.x;
    return (u16)((x + 0x7fffu + ((x>>16)&1u)) >> 16);      // RNE
}
static __device__ __forceinline__ float sigm(float a){
    return 1.f / (1.f + __expf(-a));   // saturates cleanly at +-inf
}
static __device__ __forceinline__ float tanh_(float a){
    float e = __expf(-2.f * fabsf(a));
    float t = (1.f - e) / (1.f + e);
    return __builtin_copysignf(t, a);
}

#define LFENCE() asm volatile("s_waitcnt lgkmcnt(0)" ::: "memory")
#define MFMA16(a,b,c) __builtin_amdgcn_mfma_f32_16x16x32_bf16(a,b,c,0,0,0)

static __device__ __forceinline__ float ldf(const void* p, int i, bool F32){
    return F32 ? ((const float*)p)[i] : bf2f(((const u16*)p)[i]);
}
// stage tile: [16 rows][64 bf16 cols] = 128 B rows; XOR swizzle on 16B chunks
static __device__ __forceinline__ char* stgp(char* base, int row, int off){
    return base + row*128 + (off ^ ((row & 7) << 4));
}

__global__ __launch_bounds__(256)
void rgcn_kernel(const void* __restrict__ xp_,   // [N,16]
                 const void* __restrict__ hp_,   // [N,32]
                 const void* __restrict__ wz_, const void* __restrict__ bz_,
                 const void* __restrict__ wr_, const void* __restrict__ br_,
                 const void* __restrict__ wh_, const void* __restrict__ bh_,
                 const void* __restrict__ wl_, const void* __restrict__ bl_,
                 void* __restrict__ dout_)       // out [N,8] ++ h_new [N,32]
{
    __shared__ u16 sW[3][32*WROW];     // combined bf16 weights, [true col][k+pad]
    __shared__ u16 sStage[4][16*64];   // per-wave bf16 [x|h] -> [x|hr] -> [relu(hn)|hr]
    __shared__ int sF32;

    const int tid = threadIdx.x;

    // ---- dtype detection (wave-parallel: f32 iff any low-half is insane bf16)
    if (tid < 64) {
        const u32* xw = (const u32*)xp_;
        int bad = 0;
#pragma unroll
        for (int q = 0; q < 2; q++) {
            float lo = bflo(xw[tid*2 + q]);
            if (!(fabsf(lo) <= 1e6f)) bad = 1;
        }
        unsigned long long m = __ballot(bad);
        if (tid == 0) sF32 = (m != 0ull) ? 1 : 0;
    }
    __syncthreads();
    const bool F32 = (sF32 != 0);

    // ---- COALESCED weight prep: linear reads of w ([2][48][32] row-major),
    // sum halves in regs, transpose on the LDS-write side:
    // sW[m][c][k] = bf16(w[0][k][c] + w[1][k][c]).
    {
        const void* wsrc[3] = { wz_, wr_, wh_ };
#pragma unroll
        for (int m = 0; m < 3; m++) {
            u16* dst = sW[m];
            if (F32) {
                const float* w = (const float*)wsrc[m];
                for (int o = tid; o < 384; o += 256) {          // 384 float4 = 1536 f32
                    float4 a = *(const float4*)(w + 4*o);        // w[0] half, [k][c]
                    float4 b = *(const float4*)(w + 1536 + 4*o); // w[1] half
                    int base = 4*o;
                    int k = base >> 5, c = base & 31;            // 4 consecutive c, same k
                    dst[(c+0)*WROW + k] = f2bf(a.x + b.x);
                    dst[(c+1)*WROW + k] = f2bf(a.y + b.y);
                    dst[(c+2)*WROW + k] = f2bf(a.z + b.z);
                    dst[(c+3)*WROW + k] = f2bf(a.w + b.w);
                }
            } else {
                const u16* w = (const u16*)wsrc[m];
                for (int o = tid; o < 192; o += 256) {           // 192 uint4 = 1536 u16
                    uint4 a = *(const uint4*)(w + 8*o);
                    uint4 b = *(const uint4*)(w + 1536 + 8*o);
                    int base = 8*o;
                    int k = base >> 5, c = base & 31;            // 8 consecutive c, same k
                    const u32 aw[4] = {a.x, a.y, a.z, a.w};
                    const u32 bw[4] = {b.x, b.y, b.z, b.w};
#pragma unroll
                    for (int q = 0; q < 4; q++) {
                        dst[(c+2*q+0)*WROW + k] = f2bf(bflo(aw[q]) + bflo(bw[q]));
                        dst[(c+2*q+1)*WROW + k] = f2bf(bfhi(aw[q]) + bfhi(bw[q]));
                    }
                }
            }
        }
        // zero the k-pad rows (k = 48..63) once, coalesced over threads
        for (int o = tid; o < 32*16; o += 256) {
            int c = o >> 4, k = 48 + (o & 15);
            sW[0][c*WROW + k] = 0; sW[1][c*WROW + k] = 0; sW[2][c*WROW + k] = 0;
        }
    }
    __syncthreads();

    const int lane = tid & 63, wv = tid >> 6;
    const int c16 = lane & 15, g = lane >> 4;     // MFMA frag coords
    const int row4 = lane >> 2, q4 = lane & 3;    // staging coords
    char* stage = (char*)sStage[wv];

    // ---- loop-invariant LDS pointers
    char* pXw = stgp(stage, row4, q4*8);            // x stage write (8B)
    char* pHw = stgp(stage, row4, 32 + q4*16);      // h stage write (16B)
    char* pA0 = stgp(stage, c16, 16*g);             // A frag k 0..31 (also relu(hn))
    char* pA1 = stgp(stage, c16, 64 + 16*g);        // A frag k 32..63
    char* pPairH[4]; char* pPairR[4];
#pragma unroll
    for (int rr = 0; rr < 4; rr++) {
        int nl = g*4 + rr;
        pPairH[rr] = stgp(stage, nl, 32 + 4*c16);   // h/hr pair (cols 2c16,2c16+1)
        pPairR[rr] = stgp(stage, nl, 4*c16);        // relu(hn) pair
    }

    // zero K-pad (stage bytes 96..127 per row = cols 48..63), once
    {
        uint2 z2; z2.x = 0u; z2.y = 0u;
        *(uint2*)stgp(stage, row4, 96 + q4*8) = z2;
    }

    // ---- biases (permuted columns: tt covers col 2*c16+tt)
    float bzv[2], brv[2], bhv[2];
#pragma unroll
    for (int tt = 0; tt < 2; tt++) {
        bzv[tt] = ldf(bz_, 2*c16 + tt, F32);
        brv[tt] = ldf(br_, 2*c16 + tt, F32);
        bhv[tt] = ldf(bh_, 2*c16 + tt, F32);
    }
    float blv = (c16 < OUT_DIM) ? ldf(bl_, c16, F32) : 0.f;

    // ---- B-fragments from LDS weight images (12 ds_read_b128 per wave)
    // B layout: lane (c16,g) covers TRUE col 2*c16+tt, k = kt*32 + g*8 + e.
    bf16x8 Bz[2][2], Br[2][2], Bh[2][2], Bl;
#pragma unroll
    for (int kt = 0; kt < 2; kt++) {
#pragma unroll
        for (int tt = 0; tt < 2; tt++) {
            int boff = (2*c16 + tt)*(WROW*2) + (kt*32 + g*8)*2;
            Bz[kt][tt] = *(const bf16x8*)((const char*)sW[0] + boff);
            Br[kt][tt] = *(const bf16x8*)((const char*)sW[1] + boff);
            Bh[kt][tt] = *(const bf16x8*)((const char*)sW[2] + boff);
        }
    }
    {
        union { u16 us[8]; bf16x8 v; } ul;
#pragma unroll
        for (int e = 0; e < 8; e++) {
            int k = g*8 + e;
            float v = (c16 < OUT_DIM) ? ldf(wl_, k*OUT_DIM + c16, F32) : 0.f;
            ul.us[e] = f2bf(v);
        }
        Bl = ul.v;
    }

    // global output bases
    float* outF = (float*)dout_;
    float* hnF  = outF + (size_t)N_NODES * OUT_DIM;
    u16*   outB = (u16*)dout_;
    u16*   hnB  = outB + (size_t)N_NODES * OUT_DIM;

    const int wid = blockIdx.x*4 + wv;
    const int nw  = gridDim.x*4;

    // ---- prefetch registers (next tile's x/h, raw bits in float4 lanes)
    float4 pfx, pfh0, pfh1;
#define PLOAD(TT) do { \
        size_t nbp = (size_t)(TT) * 16; \
        if (F32) { \
            const float* xb = (const float*)xp_ + nbp*IN_DIM; \
            pfx  = *(const float4*)(xb + row4*IN_DIM + q4*4); \
            const float* hb = (const float*)hp_ + nbp*HID; \
            pfh0 = *(const float4*)(hb + row4*HID + q4*8); \
            pfh1 = *(const float4*)(hb + row4*HID + q4*8 + 4); \
        } else { \
            const u16* xb = (const u16*)xp_ + nbp*IN_DIM; \
            uint2 xv = *(const uint2*)(xb + row4*IN_DIM + q4*4); \
            pfx.x = u2f(xv.x); pfx.y = u2f(xv.y); \
            const u16* hb = (const u16*)hp_ + nbp*HID; \
            uint4 hv = *(const uint4*)(hb + row4*HID + q4*8); \
            pfh0.x = u2f(hv.x); pfh0.y = u2f(hv.y); pfh0.z = u2f(hv.z); pfh0.w = u2f(hv.w); \
        } \
    } while (0)

    if (wid < NTILES) PLOAD(wid);

    for (int t = wid; t < NTILES; t += nw) {
        const size_t nb = (size_t)t * 16;

        // ---- stage current tile from prefetched regs (bf16 pack + ds_write)
        if (F32) {
            uint2 xp2; xp2.x = cvtpk(pfx.x, pfx.y); xp2.y = cvtpk(pfx.z, pfx.w);
            *(uint2*)pXw = xp2;
            uint4 hp4; hp4.x = cvtpk(pfh0.x, pfh0.y); hp4.y = cvtpk(pfh0.z, pfh0.w);
            hp4.z = cvtpk(pfh1.x, pfh1.y); hp4.w = cvtpk(pfh1.z, pfh1.w);
            *(uint4*)pHw = hp4;
        } else {
            uint2 xp2; xp2.x = f2u(pfx.x); xp2.y = f2u(pfx.y);
            *(uint2*)pXw = xp2;
            uint4 hp4; hp4.x = f2u(pfh0.x); hp4.y = f2u(pfh0.y);
            hp4.z = f2u(pfh0.z); hp4.w = f2u(pfh0.w);
            *(uint4*)pHw = hp4;
        }

        // ---- issue NEXT tile's global loads now; consumed next iteration,
        // so their latency hides under this tile's whole compute chain.
        {
            int tn = t + nw;
            if (tn < NTILES) PLOAD(tn);
        }
        LFENCE();

        // ---- A1 = [x | h] fragments + h pairs (read-before-overwrite)
        bf16x8 a0 = *(const bf16x8*)pA0;
        bf16x8 a1 = *(const bf16x8*)pA1;
        u32 hwp[4];
#pragma unroll
        for (int rr = 0; rr < 4; rr++) hwp[rr] = *(const u32*)pPairH[rr];

        // ---- GEMM1: z and r (permuted cols), bias-seeded
        f32x4 accZ[2], accR[2];
#pragma unroll
        for (int tt = 0; tt < 2; tt++) {
            f32x4 az; az[0]=bzv[tt]; az[1]=bzv[tt]; az[2]=bzv[tt]; az[3]=bzv[tt];
            az = MFMA16(a0, Bz[0][tt], az);
            az = MFMA16(a1, Bz[1][tt], az);
            accZ[tt] = az;
            f32x4 ar; ar[0]=brv[tt]; ar[1]=brv[tt]; ar[2]=brv[tt]; ar[3]=brv[tt];
            ar = MFMA16(a0, Br[0][tt], ar);
            ar = MFMA16(a1, Br[1][tt], ar);
            accR[tt] = ar;
        }

        // ---- glue 1: z/r sigmoid; hr pair -> one cvt_pk + one b32 LDS write
        float z0a[4], z1a[4], hv0[4], hv1[4];
#pragma unroll
        for (int rr = 0; rr < 4; rr++) {
            float h0 = bflo(hwp[rr]), h1 = bfhi(hwp[rr]);
            hv0[rr] = h0; hv1[rr] = h1;
            float z0 = sigm(accZ[0][rr]), z1 = sigm(accZ[1][rr]);
            z0a[rr] = z0; z1a[rr] = z1;
            float r0 = sigm(accR[0][rr]), r1 = sigm(accR[1][rr]);
            *(u32*)pPairH[rr] = cvtpk(h0*r0, h1*r1);
        }
        LFENCE();

        // ---- GEMMh: A2 = [x | h*r] (x half still valid)
        bf16x8 b0 = *(const bf16x8*)pA0;
        bf16x8 b1 = *(const bf16x8*)pA1;
        f32x4 accH[2];
#pragma unroll
        for (int tt = 0; tt < 2; tt++) {
            f32x4 ah; ah[0]=bhv[tt]; ah[1]=bhv[tt]; ah[2]=bhv[tt]; ah[3]=bhv[tt];
            ah = MFMA16(b0, Bh[0][tt], ah);
            ah = MFMA16(b1, Bh[1][tt], ah);
            accH[tt] = ah;
        }

        // ---- glue 2: hn = ht + z*(h-ht); relu(hn)->stage; hn->global DIRECT
#pragma unroll
        for (int rr = 0; rr < 4; rr++) {
            int nl = g*4 + rr;
            float t0 = tanh_(accH[0][rr]), t1 = tanh_(accH[1][rr]);
            float n0 = t0 + z0a[rr]*(hv0[rr] - t0);
            float n1 = t1 + z1a[rr]*(hv1[rr] - t1);
            *(u32*)pPairR[rr] = cvtpk(fmaxf(n0, 0.f), fmaxf(n1, 0.f));
            if (F32) {
                float2 st; st.x = n0; st.y = n1;
                *(float2*)(hnF + (nb + nl)*HID + 2*c16) = st;
            } else {
                *(u32*)(hnB + (nb + nl)*HID + 2*c16) = cvtpk(n0, n1);
            }
        }
        LFENCE();

        // ---- GEMMout: relu(hn) [16,32] @ [32,8]; store direct from acc
        bf16x8 a3 = *(const bf16x8*)pA0;
        f32x4 accO; accO[0]=blv; accO[1]=blv; accO[2]=blv; accO[3]=blv;
        accO = MFMA16(a3, Bl, accO);
        if (c16 < OUT_DIM) {
            if (F32) {
#pragma unroll
                for (int rr = 0; rr < 4; rr++)
                    outF[(nb + g*4 + rr)*OUT_DIM + c16] = accO[rr];
            } else {
#pragma unroll
                for (int rr = 0; rr < 4; rr++)
                    outB[(nb + g*4 + rr)*OUT_DIM + c16] = (u16)(cvtpk(accO[rr], accO[rr]) & 0xffffu);
            }
        }
    }
#undef PLOAD
}

extern "C" void kernel_launch(void* const* d_in, const int* in_sizes, int n_in,
                              void* d_out, int out_size, void* d_ws, size_t ws_size,
                              hipStream_t stream) {
    // setup_inputs() order:
    // 0 x, 1 edge_index(unused), 2 edge_weight(unused), 3 h,
    // 4 w_z, 5 b_z, 6 w_r, 7 b_r, 8 w_h, 9 b_h, 10 w_lin, 11 b_lin
    const int block = 256;     // 4 waves; each wave owns independent 16-node tiles
    const int grid  = 2048;    // 8192 waves, grid-stride over 31250 tiles
    rgcn_kernel<<<grid, block, 0, stream>>>(
        d_in[0], d_in[3], d_in[4], d_in[5], d_in[6], d_in[7],
        d_in[8], d_in[9], d_in[10], d_in[11], d_out);
}